// Round 5
// baseline (359.734 us; speedup 1.0000x reference)
//
#include <hip/hip_runtime.h>

// NCC loss: five 9x9x9 box sums (I, J, I^2, J^2, I*J), stride 1, pad 4,
// count_include_pad (divisor 729), ncc = cov^2/(varI*varJ+eps), out = -mean.
// Shapes fixed: [2,1,192,192,192] fp32.
//
// R5: VALU diet (R4 showed VALU-issue-bound: 52%*195us ~= static count).
//  - z-ring slots STATIC via 13 literal call sites (slot=(idx-1)%9 at compile
//    time; named locals only -> no movs, no scratch).
//  - 2 y-outputs per thread (block 16x8=128 thr): y/y+1 share 8 of 9 taps ->
//    10 LDS taps + ~55 adds per 2 outputs (was 18 + 90).
//  - float4 math to invite v_pk_add_f32.
//  - XCD-aware swizzle (id&7 -> 6x3 xy patch) for halo L2 reuse.

#define S    192
#define SS   (S * S)
#define TX   16
#define TYP  8                   // thread rows; each handles y=2*typ, 2*typ+1
#define NTHR (TX * TYP)          // 128
#define KZ   32
#define RAD  4
#define WIN  9
#define NSL  (KZ + 2 * RAD)      // 40
#define HXR  24                  // staged halo rows (16 + 8)
#define XSW  17                  // padded row stride
#define NVOX (2.0 * S * S * S)

__global__ void ncc_init(double* ws) { ws[0] = 0.0; }

__global__ void ncc_final(const double* __restrict__ ws, float* __restrict__ out) {
    out[0] = (float)(-ws[0] / NVOX);
}

__device__ __forceinline__ float4 f4add(float4 a, float4 b) {
    return make_float4(a.x + b.x, a.y + b.y, a.z + b.z, a.w + b.w);
}
__device__ __forceinline__ float4 f4sub(float4 a, float4 b) {
    return make_float4(a.x - b.x, a.y - b.y, a.z - b.z, a.w - b.w);
}

__global__ __launch_bounds__(NTHR, 3) void ncc_main(const float* __restrict__ I,
                                                    const float* __restrict__ J,
                                                    double* __restrict__ ws) {
    // LDS ~16.3 KB -> LDS allows 9 blocks/CU; VGPR (cap 170) gives ~6.
    __shared__ float4 xs4[2][HXR][XSW];   // (sI, sJ, sI2, sJ2)
    __shared__ float  xs1[2][HXR][XSW];   // sIJ
    __shared__ float  red[2];

    const int tx  = threadIdx.x;          // 0..15
    const int typ = threadIdx.y;          // 0..7
    const int tid = typ * TX + tx;        // 0..127

    // XCD-aware swizzle: id&7 = XCD (heuristic); each XCD owns a 6x3 patch of
    // 16x16 xy-tiles so halo re-fetch is L2-local. Bijective onto 12x12x12.
    const int id  = blockIdx.x;           // 0..1727
    const int xcd = id & 7;
    const int lo  = id >> 3;              // 0..215
    const int t   = lo % 18;
    const int bz  = lo / 18;              // 0..11
    const int bx  = (xcd & 1) * 6 + (t % 6);
    const int by  = (xcd >> 1) * 3 + (t / 6);
    const int b   = (bz >= 6) ? 1 : 0;
    const int zc  = bz - 6 * b;
    const int x0 = bx * TX, y0 = by * 16, z0 = zc * KZ;

    const float* Ib = I + (size_t)b * S * SS;
    const float* Jb = J + (size_t)b * S * SS;

    // x-tasks: 96 threads, task (row xr 0..23, quad xq 0..3) -> 4 outputs from
    // 12 input cols. Each float4 chunk all-valid or all-invalid (4-aligned).
    const bool xtask = (tid < 4 * HXR);
    const int  xr  = tid >> 2;
    const int  xq  = tid & 3;
    const int  gy  = y0 - RAD + xr;
    const bool gyv = ((unsigned)gy < (unsigned)S);
    const int  c0  = x0 + 4 * xq - RAD;
    const bool cv0 = gyv && ((unsigned)(c0    ) < (unsigned)S);
    const bool cv1 = gyv && ((unsigned)(c0 + 4) < (unsigned)S);
    const bool cv2 = gyv && ((unsigned)(c0 + 8) < (unsigned)S);
    const long rowoff = gyv ? ((long)gy * S + c0) : 0;   // may be -4; guarded

    float4 li0, li1, li2, lj0, lj1, lj2;

    auto load_slice = [&](int p) {
        li0 = li1 = li2 = lj0 = lj1 = lj2 = make_float4(0.f, 0.f, 0.f, 0.f);
        if (p < NSL && xtask) {
            const int zi = z0 - RAD + p;
            if ((unsigned)zi < (unsigned)S) {
                const float* rI = Ib + (size_t)zi * SS + rowoff;
                const float* rJ = Jb + (size_t)zi * SS + rowoff;
                if (cv0) { li0 = *(const float4*)(rI);     lj0 = *(const float4*)(rJ); }
                if (cv1) { li1 = *(const float4*)(rI + 4); lj1 = *(const float4*)(rJ + 4); }
                if (cv2) { li2 = *(const float4*)(rI + 8); lj2 = *(const float4*)(rJ + 8); }
            }
        }
    };

    auto xphase = [&](int p) {
        if (xtask) {
            const float iv[12] = { li0.x, li0.y, li0.z, li0.w,
                                   li1.x, li1.y, li1.z, li1.w,
                                   li2.x, li2.y, li2.z, li2.w };
            const float jv[12] = { lj0.x, lj0.y, lj0.z, lj0.w,
                                   lj1.x, lj1.y, lj1.z, lj1.w,
                                   lj2.x, lj2.y, lj2.z, lj2.w };
            float a = 0.f, bb = 0.f, c = 0.f, d = 0.f, e = 0.f;
            #pragma unroll
            for (int m = 0; m < WIN; ++m) {
                a += iv[m];
                bb += jv[m];
                c = fmaf(iv[m], iv[m], c);
                d = fmaf(jv[m], jv[m], d);
                e = fmaf(iv[m], jv[m], e);
            }
            const int cb = p & 1;
            #pragma unroll
            for (int k = 0; k < 4; ++k) {
                if (k > 0) {
                    a += iv[8 + k] - iv[k - 1];
                    bb += jv[8 + k] - jv[k - 1];
                    c += fmaf(iv[8 + k], iv[8 + k], -iv[k - 1] * iv[k - 1]);
                    d += fmaf(jv[8 + k], jv[8 + k], -jv[k - 1] * jv[k - 1]);
                    e += fmaf(iv[8 + k], jv[8 + k], -iv[k - 1] * jv[k - 1]);
                }
                xs4[cb][xr][4 * xq + k] = make_float4(a, bb, c, d);
                xs1[cb][xr][4 * xq + k] = e;
            }
        }
    };

    // z-rings: 9 slots x 2 outputs, STATIC slot index only (literal arg).
    float4 rA4[WIN], rB4[WIN];
    float  rA1[WIN], rB1[WIN];
    #pragma unroll
    for (int k = 0; k < WIN; ++k) {
        rA4[k] = rB4[k] = make_float4(0.f, 0.f, 0.f, 0.f);
        rA1[k] = rB1[k] = 0.f;
    }
    float4 runA4 = make_float4(0.f, 0.f, 0.f, 0.f);
    float4 runB4 = make_float4(0.f, 0.f, 0.f, 0.f);
    float  runA1 = 0.f, runB1 = 0.f;
    float  acc = 0.f;

    const int yA = 2 * typ;   // taps rows yA..yA+9

    auto yphase = [&](int p, int k) {   // k is ALWAYS a literal at call sites
        const int pb = p & 1;
        float4 t0_4 = xs4[pb][yA][tx];
        float  t0_1 = xs1[pb][yA][tx];
        float4 sA4 = t0_4;
        float  sA1 = t0_1;
        #pragma unroll
        for (int j = 1; j < WIN; ++j) {
            sA4 = f4add(sA4, xs4[pb][yA + j][tx]);
            sA1 += xs1[pb][yA + j][tx];
        }
        const float4 t9_4 = xs4[pb][yA + WIN][tx];
        const float  t9_1 = xs1[pb][yA + WIN][tx];
        const float4 sB4 = f4add(f4sub(sA4, t0_4), t9_4);
        const float  sB1 = sA1 - t0_1 + t9_1;

        runA4 = f4add(runA4, f4sub(sA4, rA4[k]));  rA4[k] = sA4;
        runA1 += sA1 - rA1[k];                     rA1[k] = sA1;
        runB4 = f4add(runB4, f4sub(sB4, rB4[k]));  rB4[k] = sB4;
        runB1 += sB1 - rB1[k];                     rB1[k] = sB1;

        if (p >= 2 * RAD) {
            const float inv = 1.0f / 729.0f;
            {
                const float mI  = runA4.x * inv;
                const float mJ  = runA4.y * inv;
                const float vI  = runA4.z * inv - mI * mI;
                const float vJ  = runA4.w * inv - mJ * mJ;
                const float cIJ = runA1   * inv - mI * mJ;
                acc += (cIJ * cIJ) / (vI * vJ + 1e-5f);
            }
            {
                const float mI  = runB4.x * inv;
                const float mJ  = runB4.y * inv;
                const float vI  = runB4.z * inv - mI * mI;
                const float vJ  = runB4.w * inv - mJ * mJ;
                const float cIJ = runB1   * inv - mI * mJ;
                acc += (cIJ * cIJ) / (vI * vJ + 1e-5f);
            }
        }
    };

    // Pipeline: [y(idx-1) | x(idx) | load(idx+1) | barrier].
    load_slice(0);
    xphase(0);
    load_slice(1);
    __syncthreads();

    int idx = 1;
#define BODY(K) { yphase(idx - 1, (K)); xphase(idx); load_slice(idx + 1); \
                  __syncthreads(); ++idx; }
    #pragma unroll 1
    for (int g = 0; g < 4; ++g) {      // idx 1..36, slots (idx-1)%9 = 0..8
        BODY(0) BODY(1) BODY(2) BODY(3) BODY(4)
        BODY(5) BODY(6) BODY(7) BODY(8)
    }
    BODY(0) BODY(1) BODY(2)            // idx 37,38,39 -> slots 0,1,2
    yphase(NSL - 1, 3);                // slice 39 -> slot 39%9 = 3
#undef BODY

    // Block reduction: wave shuffle -> LDS -> one double atomic
    float v = acc;
    #pragma unroll
    for (int off = 32; off >= 1; off >>= 1)
        v += __shfl_down(v, off, 64);
    const int lane = tid & 63;
    const int wid  = tid >> 6;
    if (lane == 0) red[wid] = v;
    __syncthreads();
    if (tid == 0) {
        atomicAdd(ws, (double)(red[0] + red[1]));
    }
}

extern "C" void kernel_launch(void* const* d_in, const int* in_sizes, int n_in,
                              void* d_out, int out_size, void* d_ws, size_t ws_size,
                              hipStream_t stream) {
    const float* I = (const float*)d_in[0];   // y_pred
    const float* J = (const float*)d_in[1];   // y_true
    double* ws = (double*)d_ws;
    float* out = (float*)d_out;

    hipLaunchKernelGGL(ncc_init, dim3(1), dim3(1), 0, stream, ws);

    hipLaunchKernelGGL(ncc_main, dim3(12 * 12 * 12), dim3(TX, TYP), 0, stream,
                       I, J, ws);

    hipLaunchKernelGGL(ncc_final, dim3(1), dim3(1), 0, stream, ws, out);
}

// Round 6
// 202.107 us; speedup vs baseline: 1.7799x; 1.7799x over previous
//
#include <hip/hip_runtime.h>

// NCC loss: five 9x9x9 box sums (I, J, I^2, J^2, I*J), stride 1, pad 4,
// count_include_pad (divisor 729), ncc = cov^2/(varI*varJ+eps), out = -mean.
// Shapes fixed: [2,1,192,192,192] fp32.
//
// R6: R5's plan with the spill mode removed. z-ring slots are NAMED float4/
// float scalars rotated textually by macros (literal slot tokens) -- no
// arrays, so dynamic-index demotion (R2: 62MB, R5: 270MB scratch) cannot
// happen. 16x32 tile, 256 thr, 2 adjacent y-outputs/thread (B = A - t0 + t9),
// direct-global float4 x-phase (no stage LDS), 1 barrier/slice, XCD swizzle
// (proven: FETCH 356->222MB).

#define S    192
#define SS   (S * S)
#define TX   16
#define YT   32                  // y-tile; thread (tx,tyt) owns y=2*tyt,2*tyt+1
#define NTHR 256
#define KZ   32
#define RAD  4
#define WIN  9
#define NSL  (KZ + 2 * RAD)      // 40
#define HXR  (YT + 2 * RAD)      // 40 halo rows
#define XSW  17                  // padded row stride
#define NVOX (2.0 * S * S * S)

__global__ void ncc_init(double* ws) { ws[0] = 0.0; }

__global__ void ncc_final(const double* __restrict__ ws, float* __restrict__ out) {
    out[0] = (float)(-ws[0] / NVOX);
}

__device__ __forceinline__ float4 f4add(float4 a, float4 b) {
    return make_float4(a.x + b.x, a.y + b.y, a.z + b.z, a.w + b.w);
}
__device__ __forceinline__ float4 f4sub(float4 a, float4 b) {
    return make_float4(a.x - b.x, a.y - b.y, a.z - b.z, a.w - b.w);
}

__global__ __launch_bounds__(NTHR, 2) void ncc_main(const float* __restrict__ I,
                                                    const float* __restrict__ J,
                                                    double* __restrict__ ws) {
    // LDS ~27.2 KB: xs4 2*40*17*16 + xs1 2*40*17*4 + red
    __shared__ float4 xs4[2][HXR][XSW];   // (sI, sJ, sI2, sJ2)
    __shared__ float  xs1[2][HXR][XSW];   // sIJ
    __shared__ float  red[4];

    const int tid = threadIdx.x;          // 0..255 (flat)
    const int tx  = tid & 15;
    const int tyt = tid >> 4;             // 0..15 -> outputs y=2*tyt, 2*tyt+1

    // XCD swizzle over 864 blocks: id&7 = XCD owns a 3x3 xy-patch, bijective.
    const int id  = blockIdx.x;           // 0..863
    const int xcd = id & 7;
    const int lo  = id >> 3;              // 0..107
    const int t   = lo % 9;
    const int bzq = lo / 9;               // 0..11
    const int bx  = (xcd & 3) * 3 + t % 3;     // 0..11
    const int by  = (xcd >> 2) * 3 + t / 3;    // 0..5
    const int b   = (bzq >= 6) ? 1 : 0;
    const int zc  = bzq - 6 * b;
    const int x0 = bx * TX, y0 = by * YT, z0 = zc * KZ;

    const float* Ib = I + (size_t)b * S * SS;
    const float* Jb = J + (size_t)b * S * SS;

    // x-tasks: 160 threads, task (row xr 0..39, quad xq 0..3) -> 4 x-outputs
    // from 12 input cols (4-aligned chunks, all-valid or all-invalid).
    const bool xtask = (tid < 4 * HXR);
    const int  xr  = tid >> 2;            // 0..39
    const int  xq  = tid & 3;
    const int  gy  = y0 - RAD + xr;
    const bool gyv = xtask && ((unsigned)gy < (unsigned)S);
    const int  c0  = x0 + 4 * xq - RAD;
    const bool cv0 = gyv && ((unsigned)(c0    ) < (unsigned)S);
    const bool cv1 = gyv && ((unsigned)(c0 + 4) < (unsigned)S);
    const bool cv2 = gyv && ((unsigned)(c0 + 8) < (unsigned)S);
    const ptrdiff_t rowoff = gyv ? ((ptrdiff_t)gy * S + c0) : 0;

    float4 li0, li1, li2, lj0, lj1, lj2;

    auto LOAD = [&](int p) {
        li0 = li1 = li2 = lj0 = lj1 = lj2 = make_float4(0.f, 0.f, 0.f, 0.f);
        if (p < NSL) {
            const int zi = z0 - RAD + p;
            if ((unsigned)zi < (unsigned)S) {
                const float* rI = Ib + (size_t)zi * SS + rowoff;
                const float* rJ = Jb + (size_t)zi * SS + rowoff;
                if (cv0) { li0 = *(const float4*)(rI);     lj0 = *(const float4*)(rJ); }
                if (cv1) { li1 = *(const float4*)(rI + 4); lj1 = *(const float4*)(rJ + 4); }
                if (cv2) { li2 = *(const float4*)(rI + 8); lj2 = *(const float4*)(rJ + 8); }
            }
        }
    };

    auto XPHASE = [&](int p) {
        if (xtask) {
            const float iv[12] = { li0.x, li0.y, li0.z, li0.w,
                                   li1.x, li1.y, li1.z, li1.w,
                                   li2.x, li2.y, li2.z, li2.w };
            const float jv[12] = { lj0.x, lj0.y, lj0.z, lj0.w,
                                   lj1.x, lj1.y, lj1.z, lj1.w,
                                   lj2.x, lj2.y, lj2.z, lj2.w };
            float a = 0.f, bb = 0.f, c = 0.f, d = 0.f, e = 0.f;
            #pragma unroll
            for (int m = 0; m < WIN; ++m) {
                a += iv[m];
                bb += jv[m];
                c = fmaf(iv[m], iv[m], c);
                d = fmaf(jv[m], jv[m], d);
                e = fmaf(iv[m], jv[m], e);
            }
            const int cb = p & 1;
            #pragma unroll
            for (int k = 0; k < 4; ++k) {
                if (k > 0) {
                    a += iv[8 + k] - iv[k - 1];
                    bb += jv[8 + k] - jv[k - 1];
                    c += fmaf(iv[8 + k], iv[8 + k], -iv[k - 1] * iv[k - 1]);
                    d += fmaf(jv[8 + k], jv[8 + k], -jv[k - 1] * jv[k - 1]);
                    e += fmaf(iv[8 + k], jv[8 + k], -iv[k - 1] * jv[k - 1]);
                }
                xs4[cb][xr][4 * xq + k] = make_float4(a, bb, c, d);
                xs1[cb][xr][4 * xq + k] = e;
            }
        }
    };

    // z-rings as NAMED scalars (no arrays -> no scratch demotion possible).
    const float4 F40 = make_float4(0.f, 0.f, 0.f, 0.f);
    float4 a4_0 = F40, a4_1 = F40, a4_2 = F40, a4_3 = F40, a4_4 = F40,
           a4_5 = F40, a4_6 = F40, a4_7 = F40, a4_8 = F40;
    float  a1_0 = 0.f, a1_1 = 0.f, a1_2 = 0.f, a1_3 = 0.f, a1_4 = 0.f,
           a1_5 = 0.f, a1_6 = 0.f, a1_7 = 0.f, a1_8 = 0.f;
    float4 b4_0 = F40, b4_1 = F40, b4_2 = F40, b4_3 = F40, b4_4 = F40,
           b4_5 = F40, b4_6 = F40, b4_7 = F40, b4_8 = F40;
    float  b1_0 = 0.f, b1_1 = 0.f, b1_2 = 0.f, b1_3 = 0.f, b1_4 = 0.f,
           b1_5 = 0.f, b1_6 = 0.f, b1_7 = 0.f, b1_8 = 0.f;
    float4 runA4 = F40, runB4 = F40;
    float  runA1 = 0.f, runB1 = 0.f;
    float  acc = 0.f;
    const int yA = 2 * tyt;               // taps yA..yA+9 cover both outputs

#define EMIT(R4, R1) do {                                                   \
        const float inv_ = 1.0f / 729.0f;                                   \
        const float mI_ = (R4).x * inv_, mJ_ = (R4).y * inv_;               \
        const float vI_ = (R4).z * inv_ - mI_ * mI_;                        \
        const float vJ_ = (R4).w * inv_ - mJ_ * mJ_;                        \
        const float cIJ_ = (R1) * inv_ - mI_ * mJ_;                         \
        acc += (cIJ_ * cIJ_) / (vI_ * vJ_ + 1e-5f);                         \
    } while (0)

#define YSTEP(P, K) do {                                                    \
        const int pb_ = (P) & 1;                                            \
        float4 t0_4 = xs4[pb_][yA][tx];                                     \
        float  t0_1 = xs1[pb_][yA][tx];                                     \
        float4 s4 = t0_4;                                                   \
        float  s1 = t0_1;                                                   \
        _Pragma("unroll")                                                   \
        for (int j_ = 1; j_ < WIN; ++j_) {                                  \
            s4 = f4add(s4, xs4[pb_][yA + j_][tx]);                          \
            s1 += xs1[pb_][yA + j_][tx];                                    \
        }                                                                   \
        const float4 t9_4 = xs4[pb_][yA + WIN][tx];                         \
        const float  t9_1 = xs1[pb_][yA + WIN][tx];                         \
        const float4 sB4 = f4add(f4sub(s4, t0_4), t9_4);                    \
        const float  sB1 = s1 - t0_1 + t9_1;                                \
        runA4 = f4add(runA4, f4sub(s4, a4_##K));   a4_##K = s4;             \
        runA1 += s1 - a1_##K;                      a1_##K = s1;             \
        runB4 = f4add(runB4, f4sub(sB4, b4_##K));  b4_##K = sB4;            \
        runB1 += sB1 - b1_##K;                     b1_##K = sB1;            \
        if ((P) >= 2 * RAD) { EMIT(runA4, runA1); EMIT(runB4, runB1); }     \
    } while (0)

#define BODY(K) { YSTEP(idx - 1, K); XPHASE(idx); LOAD(idx + 1);            \
                  __syncthreads(); ++idx; }

    // Pipeline: [y(idx-1) | x(idx) | load(idx+1) | barrier] per slice.
    LOAD(0);
    XPHASE(0);
    LOAD(1);
    __syncthreads();

    int idx = 1;
    #pragma unroll 1
    for (int g = 0; g < 4; ++g) {        // y-index p=idx-1 = 0..35, K=p%9
        BODY(0) BODY(1) BODY(2) BODY(3) BODY(4)
        BODY(5) BODY(6) BODY(7) BODY(8)
    }
    BODY(0) BODY(1) BODY(2)              // p = 36,37,38 -> K 0,1,2
    YSTEP(NSL - 1, 3);                   // p = 39 -> 39%9 = 3
#undef BODY
#undef YSTEP
#undef EMIT

    // Block reduction: wave shuffle -> LDS -> one double atomic
    float v = acc;
    #pragma unroll
    for (int off = 32; off >= 1; off >>= 1)
        v += __shfl_down(v, off, 64);
    const int lane = tid & 63;
    const int wid  = tid >> 6;
    if (lane == 0) red[wid] = v;
    __syncthreads();
    if (tid == 0) {
        atomicAdd(ws, (double)(red[0] + red[1] + red[2] + red[3]));
    }
}

extern "C" void kernel_launch(void* const* d_in, const int* in_sizes, int n_in,
                              void* d_out, int out_size, void* d_ws, size_t ws_size,
                              hipStream_t stream) {
    const float* I = (const float*)d_in[0];   // y_pred
    const float* J = (const float*)d_in[1];   // y_true
    double* ws = (double*)d_ws;
    float* out = (float*)d_out;

    hipLaunchKernelGGL(ncc_init, dim3(1), dim3(1), 0, stream, ws);

    hipLaunchKernelGGL(ncc_main, dim3(12 * 6 * 12), dim3(NTHR), 0, stream,
                       I, J, ws);

    hipLaunchKernelGGL(ncc_final, dim3(1), dim3(1), 0, stream, ws, out);
}

// Round 7
// 201.279 us; speedup vs baseline: 1.7872x; 1.0041x over previous
//
#include <hip/hip_runtime.h>

// NCC loss: five 9x9x9 box sums (I, J, I^2, J^2, I*J), stride 1, pad 4,
// count_include_pad (divisor 729), ncc = cov^2/(varI*varJ+eps), out = -mean.
// Shapes fixed: [2,1,192,192,192] fp32.
//
// R7 = R6 + two counter-driven fixes:
//  (1) slice-loop barrier is hand-rolled "s_waitcnt lgkmcnt(0); s_barrier"
//      -- __syncthreads() emits vmcnt(0) too, which drained the global
//      prefetch every slice (the ~40us stall gap R6 showed). LDS visibility
//      across waves needs only lgkmcnt+barrier; global loads stay in flight.
//  (2) xs1 row stride 17 -> 20 floats: y-phase b32 reads hit banks 8t+tx
//      (exact 2-way aliasing = free) instead of ~4-way over 22 banks.
// Carried from R6: named-scalar z-rings (no arrays -> no scratch), 16x32
// tile, 2 adjacent y-outputs/thread, direct-global float4 x-phase, XCD
// swizzle (FETCH == compulsory 116MB).

#define S    192
#define SS   (S * S)
#define TX   16
#define YT   32                  // y-tile; thread (tx,tyt) owns y=2*tyt,2*tyt+1
#define NTHR 256
#define KZ   32
#define RAD  4
#define WIN  9
#define NSL  (KZ + 2 * RAD)      // 40
#define HXR  (YT + 2 * RAD)      // 40 halo rows
#define XSW  17                  // xs4 padded row stride (float4 units)
#define XSW1 20                  // xs1 padded row stride (floats): banks 8t+tx
#define NVOX (2.0 * S * S * S)

// LDS-only barrier: waves' DS ops complete (lgkmcnt) + rendezvous. No vmcnt
// drain -> global prefetch survives the barrier.
#define LDS_BARRIER() __asm__ __volatile__("s_waitcnt lgkmcnt(0)\n\ts_barrier" ::: "memory")

__global__ void ncc_init(double* ws) { ws[0] = 0.0; }

__global__ void ncc_final(const double* __restrict__ ws, float* __restrict__ out) {
    out[0] = (float)(-ws[0] / NVOX);
}

__device__ __forceinline__ float4 f4add(float4 a, float4 b) {
    return make_float4(a.x + b.x, a.y + b.y, a.z + b.z, a.w + b.w);
}
__device__ __forceinline__ float4 f4sub(float4 a, float4 b) {
    return make_float4(a.x - b.x, a.y - b.y, a.z - b.z, a.w - b.w);
}

__global__ __launch_bounds__(NTHR, 2) void ncc_main(const float* __restrict__ I,
                                                    const float* __restrict__ J,
                                                    double* __restrict__ ws) {
    // LDS ~28 KB: xs4 2*40*17*16 + xs1 2*40*20*4 + red
    __shared__ float4 xs4[2][HXR][XSW];    // (sI, sJ, sI2, sJ2)
    __shared__ float  xs1[2][HXR][XSW1];   // sIJ
    __shared__ float  red[4];

    const int tid = threadIdx.x;          // 0..255 (flat)
    const int tx  = tid & 15;
    const int tyt = tid >> 4;             // 0..15 -> outputs y=2*tyt, 2*tyt+1

    // XCD swizzle over 864 blocks: id&7 = XCD owns a 3x3 xy-patch, bijective.
    const int id  = blockIdx.x;           // 0..863
    const int xcd = id & 7;
    const int lo  = id >> 3;              // 0..107
    const int t   = lo % 9;
    const int bzq = lo / 9;               // 0..11
    const int bx  = (xcd & 3) * 3 + t % 3;     // 0..11
    const int by  = (xcd >> 2) * 3 + t / 3;    // 0..5
    const int b   = (bzq >= 6) ? 1 : 0;
    const int zc  = bzq - 6 * b;
    const int x0 = bx * TX, y0 = by * YT, z0 = zc * KZ;

    const float* Ib = I + (size_t)b * S * SS;
    const float* Jb = J + (size_t)b * S * SS;

    // x-tasks: 160 threads, task (row xr 0..39, quad xq 0..3) -> 4 x-outputs
    // from 12 input cols (4-aligned chunks, all-valid or all-invalid).
    const bool xtask = (tid < 4 * HXR);
    const int  xr  = tid >> 2;            // 0..39
    const int  xq  = tid & 3;
    const int  gy  = y0 - RAD + xr;
    const bool gyv = xtask && ((unsigned)gy < (unsigned)S);
    const int  c0  = x0 + 4 * xq - RAD;
    const bool cv0 = gyv && ((unsigned)(c0    ) < (unsigned)S);
    const bool cv1 = gyv && ((unsigned)(c0 + 4) < (unsigned)S);
    const bool cv2 = gyv && ((unsigned)(c0 + 8) < (unsigned)S);
    const ptrdiff_t rowoff = gyv ? ((ptrdiff_t)gy * S + c0) : 0;

    float4 li0, li1, li2, lj0, lj1, lj2;

    auto LOAD = [&](int p) {
        li0 = li1 = li2 = lj0 = lj1 = lj2 = make_float4(0.f, 0.f, 0.f, 0.f);
        if (p < NSL) {
            const int zi = z0 - RAD + p;
            if ((unsigned)zi < (unsigned)S) {
                const float* rI = Ib + (size_t)zi * SS + rowoff;
                const float* rJ = Jb + (size_t)zi * SS + rowoff;
                if (cv0) { li0 = *(const float4*)(rI);     lj0 = *(const float4*)(rJ); }
                if (cv1) { li1 = *(const float4*)(rI + 4); lj1 = *(const float4*)(rJ + 4); }
                if (cv2) { li2 = *(const float4*)(rI + 8); lj2 = *(const float4*)(rJ + 8); }
            }
        }
    };

    auto XPHASE = [&](int p) {
        if (xtask) {
            const float iv[12] = { li0.x, li0.y, li0.z, li0.w,
                                   li1.x, li1.y, li1.z, li1.w,
                                   li2.x, li2.y, li2.z, li2.w };
            const float jv[12] = { lj0.x, lj0.y, lj0.z, lj0.w,
                                   lj1.x, lj1.y, lj1.z, lj1.w,
                                   lj2.x, lj2.y, lj2.z, lj2.w };
            float a = 0.f, bb = 0.f, c = 0.f, d = 0.f, e = 0.f;
            #pragma unroll
            for (int m = 0; m < WIN; ++m) {
                a += iv[m];
                bb += jv[m];
                c = fmaf(iv[m], iv[m], c);
                d = fmaf(jv[m], jv[m], d);
                e = fmaf(iv[m], jv[m], e);
            }
            const int cb = p & 1;
            #pragma unroll
            for (int k = 0; k < 4; ++k) {
                if (k > 0) {
                    a += iv[8 + k] - iv[k - 1];
                    bb += jv[8 + k] - jv[k - 1];
                    c += fmaf(iv[8 + k], iv[8 + k], -iv[k - 1] * iv[k - 1]);
                    d += fmaf(jv[8 + k], jv[8 + k], -jv[k - 1] * jv[k - 1]);
                    e += fmaf(iv[8 + k], jv[8 + k], -iv[k - 1] * jv[k - 1]);
                }
                xs4[cb][xr][4 * xq + k] = make_float4(a, bb, c, d);
                xs1[cb][xr][4 * xq + k] = e;
            }
        }
    };

    // z-rings as NAMED scalars (no arrays -> no scratch demotion possible).
    const float4 F40 = make_float4(0.f, 0.f, 0.f, 0.f);
    float4 a4_0 = F40, a4_1 = F40, a4_2 = F40, a4_3 = F40, a4_4 = F40,
           a4_5 = F40, a4_6 = F40, a4_7 = F40, a4_8 = F40;
    float  a1_0 = 0.f, a1_1 = 0.f, a1_2 = 0.f, a1_3 = 0.f, a1_4 = 0.f,
           a1_5 = 0.f, a1_6 = 0.f, a1_7 = 0.f, a1_8 = 0.f;
    float4 b4_0 = F40, b4_1 = F40, b4_2 = F40, b4_3 = F40, b4_4 = F40,
           b4_5 = F40, b4_6 = F40, b4_7 = F40, b4_8 = F40;
    float  b1_0 = 0.f, b1_1 = 0.f, b1_2 = 0.f, b1_3 = 0.f, b1_4 = 0.f,
           b1_5 = 0.f, b1_6 = 0.f, b1_7 = 0.f, b1_8 = 0.f;
    float4 runA4 = F40, runB4 = F40;
    float  runA1 = 0.f, runB1 = 0.f;
    float  acc = 0.f;
    const int yA = 2 * tyt;               // taps yA..yA+9 cover both outputs

#define EMIT(R4, R1) do {                                                   \
        const float inv_ = 1.0f / 729.0f;                                   \
        const float mI_ = (R4).x * inv_, mJ_ = (R4).y * inv_;               \
        const float vI_ = (R4).z * inv_ - mI_ * mI_;                        \
        const float vJ_ = (R4).w * inv_ - mJ_ * mJ_;                        \
        const float cIJ_ = (R1) * inv_ - mI_ * mJ_;                         \
        acc += (cIJ_ * cIJ_) / (vI_ * vJ_ + 1e-5f);                         \
    } while (0)

#define YSTEP(P, K) do {                                                    \
        const int pb_ = (P) & 1;                                            \
        float4 t0_4 = xs4[pb_][yA][tx];                                     \
        float  t0_1 = xs1[pb_][yA][tx];                                     \
        float4 s4 = t0_4;                                                   \
        float  s1 = t0_1;                                                   \
        _Pragma("unroll")                                                   \
        for (int j_ = 1; j_ < WIN; ++j_) {                                  \
            s4 = f4add(s4, xs4[pb_][yA + j_][tx]);                          \
            s1 += xs1[pb_][yA + j_][tx];                                    \
        }                                                                   \
        const float4 t9_4 = xs4[pb_][yA + WIN][tx];                         \
        const float  t9_1 = xs1[pb_][yA + WIN][tx];                         \
        const float4 sB4 = f4add(f4sub(s4, t0_4), t9_4);                    \
        const float  sB1 = s1 - t0_1 + t9_1;                                \
        runA4 = f4add(runA4, f4sub(s4, a4_##K));   a4_##K = s4;             \
        runA1 += s1 - a1_##K;                      a1_##K = s1;             \
        runB4 = f4add(runB4, f4sub(sB4, b4_##K));  b4_##K = sB4;            \
        runB1 += sB1 - b1_##K;                     b1_##K = sB1;            \
        if ((P) >= 2 * RAD) { EMIT(runA4, runA1); EMIT(runB4, runB1); }     \
    } while (0)

#define BODY(K) { YSTEP(idx - 1, K); XPHASE(idx); LOAD(idx + 1);            \
                  LDS_BARRIER(); ++idx; }

    // Pipeline: [y(idx-1) | x(idx) | load(idx+1) | lds-barrier] per slice.
    LOAD(0);
    XPHASE(0);
    LOAD(1);
    LDS_BARRIER();

    int idx = 1;
    #pragma unroll 1
    for (int g = 0; g < 4; ++g) {        // y-index p=idx-1 = 0..35, K=p%9
        BODY(0) BODY(1) BODY(2) BODY(3) BODY(4)
        BODY(5) BODY(6) BODY(7) BODY(8)
    }
    BODY(0) BODY(1) BODY(2)              // p = 36,37,38 -> K 0,1,2
    YSTEP(NSL - 1, 3);                   // p = 39 -> 39%9 = 3
#undef BODY
#undef YSTEP
#undef EMIT

    // Block reduction: wave shuffle -> LDS -> one double atomic.
    // (Full __syncthreads here is fine: once per block, nothing to prefetch.)
    float v = acc;
    #pragma unroll
    for (int off = 32; off >= 1; off >>= 1)
        v += __shfl_down(v, off, 64);
    const int lane = tid & 63;
    const int wid  = tid >> 6;
    if (lane == 0) red[wid] = v;
    __syncthreads();
    if (tid == 0) {
        atomicAdd(ws, (double)(red[0] + red[1] + red[2] + red[3]));
    }
}

extern "C" void kernel_launch(void* const* d_in, const int* in_sizes, int n_in,
                              void* d_out, int out_size, void* d_ws, size_t ws_size,
                              hipStream_t stream) {
    const float* I = (const float*)d_in[0];   // y_pred
    const float* J = (const float*)d_in[1];   // y_true
    double* ws = (double*)d_ws;
    float* out = (float*)d_out;

    hipLaunchKernelGGL(ncc_init, dim3(1), dim3(1), 0, stream, ws);

    hipLaunchKernelGGL(ncc_main, dim3(12 * 6 * 12), dim3(NTHR), 0, stream,
                       I, J, ws);

    hipLaunchKernelGGL(ncc_final, dim3(1), dim3(1), 0, stream, ws, out);
}